// Round 1
// baseline (539.767 us; speedup 1.0000x reference)
//
#include <hip/hip_runtime.h>
#include <math.h>

// Problem: out[b,i,j] = (i==j) + sum_k F[i,k]F[j,k] + s[b]*x[b,i]*x[b,j]
//   with F = metric_factors[chart], s[b] = 1 - sum_k softmax(x[b])_k^2
// B=2048, D=256, fp32. Write-BW bound: 512 MiB output.
//
// v2 structure:
//   kernel 1: base = I + F F^T (unchanged, tiny)
//   kernel 2: s[b] only (wave-per-row, 512 blocks)
//   kernel 3: tiled writer — each block owns (16 batches) x (32-row band).
//     base band lives in REGISTERS (8 float4/thread, 16x reuse vs v1's
//     per-batch full-base re-read: 512 MiB -> 32 MiB read traffic),
//     x rows staged in LDS, output written with NONTEMPORAL float4 stores
//     (streaming, never re-read -> don't allocate in L2).

#define DIM 256
#define BATCH 2048
#define NB 16   // batches per block
#define RB 32   // output rows per block

typedef float f4 __attribute__((ext_vector_type(4)));

// ---------------- kernel 1: base = I + F F^T  (D x D) ----------------
__global__ __launch_bounds__(256) void base_kernel(const float* __restrict__ mf,
                                                   const int* __restrict__ chart,
                                                   float* __restrict__ base) {
    const float* F = mf + (size_t)chart[0] * DIM * DIM;
    __shared__ float As[32][33];
    __shared__ float Bs[32][33];
    const int tx = threadIdx.x, ty = threadIdx.y;
    const int tid = ty * 16 + tx;           // 0..255
    const int i0 = blockIdx.y * 32, j0 = blockIdx.x * 32;
    float acc00 = 0.f, acc01 = 0.f, acc10 = 0.f, acc11 = 0.f;

    const int lrow = tid >> 3;              // 0..31
    const int lc4  = (tid & 7) * 4;         // 0,4,...,28

    for (int k0 = 0; k0 < DIM; k0 += 32) {
        float4 a = *(const float4*)(F + (size_t)(i0 + lrow) * DIM + k0 + lc4);
        float4 b = *(const float4*)(F + (size_t)(j0 + lrow) * DIM + k0 + lc4);
        As[lrow][lc4 + 0] = a.x; As[lrow][lc4 + 1] = a.y;
        As[lrow][lc4 + 2] = a.z; As[lrow][lc4 + 3] = a.w;
        Bs[lrow][lc4 + 0] = b.x; Bs[lrow][lc4 + 1] = b.y;
        Bs[lrow][lc4 + 2] = b.z; Bs[lrow][lc4 + 3] = b.w;
        __syncthreads();
        #pragma unroll
        for (int kk = 0; kk < 32; ++kk) {
            float a0 = As[ty * 2 + 0][kk];
            float a1 = As[ty * 2 + 1][kk];
            float b0 = Bs[tx * 2 + 0][kk];
            float b1 = Bs[tx * 2 + 1][kk];
            acc00 += a0 * b0; acc01 += a0 * b1;
            acc10 += a1 * b0; acc11 += a1 * b1;
        }
        __syncthreads();
    }
    const int i = i0 + ty * 2, j = j0 + tx * 2;
    base[(size_t)(i + 0) * DIM + (j + 0)] = acc00 + ((i + 0) == (j + 0) ? 1.0f : 0.0f);
    base[(size_t)(i + 0) * DIM + (j + 1)] = acc01 + ((i + 0) == (j + 1) ? 1.0f : 0.0f);
    base[(size_t)(i + 1) * DIM + (j + 0)] = acc10 + ((i + 1) == (j + 0) ? 1.0f : 0.0f);
    base[(size_t)(i + 1) * DIM + (j + 1)] = acc11 + ((i + 1) == (j + 1) ? 1.0f : 0.0f);
}

// ---------------- kernel 2: s[b] = 1 - sum_k softmax(x[b])_k^2 ----------------
// One wave per row; lane l holds x[row, 4l..4l+3].
__global__ __launch_bounds__(256) void s_kernel(const float* __restrict__ x,
                                                float* __restrict__ s) {
    const int row  = blockIdx.x * 4 + (threadIdx.x >> 6);
    const int lane = threadIdx.x & 63;
    const float4 v = *(const float4*)(x + (size_t)row * DIM + lane * 4);
    float m = fmaxf(fmaxf(v.x, v.y), fmaxf(v.z, v.w));
    #pragma unroll
    for (int off = 32; off; off >>= 1) m = fmaxf(m, __shfl_xor(m, off));
    const float e0 = __expf(v.x - m), e1 = __expf(v.y - m);
    const float e2 = __expf(v.z - m), e3 = __expf(v.w - m);
    float z = e0 + e1 + e2 + e3;
    float q = e0 * e0 + e1 * e1 + e2 * e2 + e3 * e3;
    #pragma unroll
    for (int off = 32; off; off >>= 1) { z += __shfl_xor(z, off); q += __shfl_xor(q, off); }
    if (lane == 0) s[row] = 1.0f - q / (z * z);
}

// ---------------- kernel 3: tiled writer ----------------
// grid (BATCH/NB, DIM/RB) = (128, 8), block 256.
// thread t: irow = t>>6 (0..3), j4 = t&63 (float4 column).
// breg[k] = base[i0 + k*4 + irow][4*j4 ..], k = 0..7  (covers the 32-row band)
__global__ __launch_bounds__(256) void main_kernel(const float* __restrict__ x,
                                                   const float* __restrict__ s,
                                                   const float* __restrict__ base,
                                                   float* __restrict__ out) {
    const int t  = threadIdx.x;
    const int b0 = blockIdx.x * NB;
    const int i0 = blockIdx.y * RB;

    __shared__ float xs[NB][DIM];    // 16 KiB: x rows b0..b0+15
    __shared__ float sxs[NB][RB];    // 2 KiB:  s[b]*x[b, i0+r]

    // base band -> registers. lin = k*256 + t maps exactly to
    // (row = k*4 + irow, col4 = j4): coalesced 4 KiB loads per k.
    f4 breg[8];
    const f4* base4 = (const f4*)(base + (size_t)i0 * DIM);
    #pragma unroll
    for (int k = 0; k < 8; ++k) breg[k] = base4[k * 256 + t];

    // stage x rows (contiguous copy of 16 KiB)
    {
        const f4* xg = (const f4*)(x + (size_t)b0 * DIM);
        f4* xl = (f4*)xs;
        #pragma unroll
        for (int k = 0; k < 4; ++k) xl[k * 256 + t] = xg[k * 256 + t];
    }
    // stage s[b]*x[b, band]
    #pragma unroll
    for (int k = 0; k < 2; ++k) {
        const int lin = k * 256 + t;        // 0..511
        const int bb = lin >> 5, r = lin & 31;
        sxs[bb][r] = s[b0 + bb] * x[(size_t)(b0 + bb) * DIM + i0 + r];
    }
    __syncthreads();

    const int irow = t >> 6, j4 = t & 63;
    float* outp = out + (size_t)b0 * DIM * DIM + (size_t)i0 * DIM;

    for (int b = 0; b < NB; ++b) {
        const f4 xj = ((const f4*)xs[b])[j4];
        f4* o4 = (f4*)(outp + (size_t)b * DIM * DIM);
        #pragma unroll
        for (int k = 0; k < 8; ++k) {
            const float sxv = sxs[b][k * 4 + irow];   // wave-uniform -> LDS broadcast
            f4 v = breg[k] + sxv * xj;
            __builtin_nontemporal_store(v, o4 + (k * 4 + irow) * 64 + j4);
        }
    }
}

extern "C" void kernel_launch(void* const* d_in, const int* in_sizes, int n_in,
                              void* d_out, int out_size, void* d_ws, size_t ws_size,
                              hipStream_t stream) {
    const float* x  = (const float*)d_in[0];               // [2048, 256]
    const float* mf = (const float*)d_in[1];               // [4, 256, 256]
    const int* chart = (const int*)d_in[2];                // scalar
    float* out  = (float*)d_out;                           // [2048, 256, 256]
    float* base = (float*)d_ws;                            // 256*256 floats = 256 KiB
    float* s    = base + DIM * DIM;                        // 2048 floats

    base_kernel<<<dim3(8, 8), dim3(16, 16), 0, stream>>>(mf, chart, base);
    s_kernel<<<dim3(BATCH / 4), dim3(256), 0, stream>>>(x, s);
    main_kernel<<<dim3(BATCH / NB, DIM / RB), dim3(256), 0, stream>>>(x, s, base, out);
}

// Round 2
// 533.839 us; speedup vs baseline: 1.0111x; 1.0111x over previous
//
#include <hip/hip_runtime.h>
#include <math.h>

// Problem: out[b,i,j] = (i==j) + sum_k F[i,k]F[j,k] + s[b]*x[b,i]*x[b,j]
//   with F = metric_factors[chart], s[b] = 1 - sum_k softmax(x[b])_k^2
// B=2048, D=256, fp32. Write-BW bound: 512 MiB output.
//
// v3 (discriminator round):
//   kernel 1 (fused_prep): base = I + F F^T  AND  s[b], one launch.
//   kernel 2 (main): NB=8 batches x RB=32 rows per block -> 2048 blocks
//     (8 blocks/CU, 32 waves/CU = max occupancy). Each wave stores 8
//     CONSECUTIVE rows per batch (8 KiB contiguous spans). Plain stores.

#define DIM 256
#define BATCH 2048
#define NB 8    // batches per block
#define RB 32   // output rows per block

typedef float f4 __attribute__((ext_vector_type(4)));

// ---------------- kernel 1: fused base (I + F F^T) and s[b] ----------------
// grid 576 blocks: blocks 0..63 compute base tiles, blocks 64..575 compute s.
__global__ __launch_bounds__(256) void prep_kernel(const float* __restrict__ mf,
                                                   const int* __restrict__ chart,
                                                   const float* __restrict__ x,
                                                   float* __restrict__ base,
                                                   float* __restrict__ s) {
    if (blockIdx.x >= 64) {
        // ---- s path: one wave per batch row ----
        const int row  = (blockIdx.x - 64) * 4 + (threadIdx.x >> 6);
        const int lane = threadIdx.x & 63;
        const float4 v = *(const float4*)(x + (size_t)row * DIM + lane * 4);
        float m = fmaxf(fmaxf(v.x, v.y), fmaxf(v.z, v.w));
        #pragma unroll
        for (int off = 32; off; off >>= 1) m = fmaxf(m, __shfl_xor(m, off));
        const float e0 = __expf(v.x - m), e1 = __expf(v.y - m);
        const float e2 = __expf(v.z - m), e3 = __expf(v.w - m);
        float z = e0 + e1 + e2 + e3;
        float q = e0 * e0 + e1 * e1 + e2 * e2 + e3 * e3;
        #pragma unroll
        for (int off = 32; off; off >>= 1) { z += __shfl_xor(z, off); q += __shfl_xor(q, off); }
        if (lane == 0) s[row] = 1.0f - q / (z * z);
        return;
    }
    // ---- base path: 32x32 tile of I + F F^T ----
    const float* F = mf + (size_t)chart[0] * DIM * DIM;
    __shared__ float As[32][33];
    __shared__ float Bs[32][33];
    const int tid = threadIdx.x;            // 0..255
    const int tx = tid & 15, ty = tid >> 4;
    const int i0 = (blockIdx.x >> 3) * 32, j0 = (blockIdx.x & 7) * 32;
    float acc00 = 0.f, acc01 = 0.f, acc10 = 0.f, acc11 = 0.f;

    const int lrow = tid >> 3;              // 0..31
    const int lc4  = (tid & 7) * 4;         // 0,4,...,28

    for (int k0 = 0; k0 < DIM; k0 += 32) {
        float4 a = *(const float4*)(F + (size_t)(i0 + lrow) * DIM + k0 + lc4);
        float4 b = *(const float4*)(F + (size_t)(j0 + lrow) * DIM + k0 + lc4);
        As[lrow][lc4 + 0] = a.x; As[lrow][lc4 + 1] = a.y;
        As[lrow][lc4 + 2] = a.z; As[lrow][lc4 + 3] = a.w;
        Bs[lrow][lc4 + 0] = b.x; Bs[lrow][lc4 + 1] = b.y;
        Bs[lrow][lc4 + 2] = b.z; Bs[lrow][lc4 + 3] = b.w;
        __syncthreads();
        #pragma unroll
        for (int kk = 0; kk < 32; ++kk) {
            float a0 = As[ty * 2 + 0][kk];
            float a1 = As[ty * 2 + 1][kk];
            float b0 = Bs[tx * 2 + 0][kk];
            float b1 = Bs[tx * 2 + 1][kk];
            acc00 += a0 * b0; acc01 += a0 * b1;
            acc10 += a1 * b0; acc11 += a1 * b1;
        }
        __syncthreads();
    }
    const int i = i0 + ty * 2, j = j0 + tx * 2;
    base[(size_t)(i + 0) * DIM + (j + 0)] = acc00 + ((i + 0) == (j + 0) ? 1.0f : 0.0f);
    base[(size_t)(i + 0) * DIM + (j + 1)] = acc01 + ((i + 0) == (j + 1) ? 1.0f : 0.0f);
    base[(size_t)(i + 1) * DIM + (j + 0)] = acc10 + ((i + 1) == (j + 0) ? 1.0f : 0.0f);
    base[(size_t)(i + 1) * DIM + (j + 1)] = acc11 + ((i + 1) == (j + 1) ? 1.0f : 0.0f);
}

// ---------------- kernel 2: tiled writer ----------------
// grid (BATCH/NB, DIM/RB) = (256, 8), block 256 -> 2048 blocks, 8/CU.
// thread t: irow = t>>6 (0..3), j4 = t&63.
// Wave irow owns rows [i0 + irow*8, i0 + irow*8 + 8): contiguous 8 KiB span
// per batch. breg[k] = base[i0 + irow*8 + k][4*j4..] (k = 0..7).
__global__ __launch_bounds__(256) void main_kernel(const float* __restrict__ x,
                                                   const float* __restrict__ s,
                                                   const float* __restrict__ base,
                                                   float* __restrict__ out) {
    const int t  = threadIdx.x;
    const int b0 = blockIdx.x * NB;
    const int i0 = blockIdx.y * RB;
    const int irow = t >> 6, j4 = t & 63;

    __shared__ float xs[NB][DIM];    // 8 KiB: x rows b0..b0+7
    __shared__ float sxs[NB][RB];    // 1 KiB: s[b]*x[b, i0+r]

    // base band -> registers: wave irow loads its 8 consecutive rows.
    f4 breg[8];
    const f4* base4 = (const f4*)(base + (size_t)i0 * DIM);
    #pragma unroll
    for (int k = 0; k < 8; ++k) breg[k] = base4[(irow * 8 + k) * 64 + j4];

    // stage x rows (contiguous copy of 8 KiB = 512 f4, 2 per thread)
    {
        const f4* xg = (const f4*)(x + (size_t)b0 * DIM);
        f4* xl = (f4*)xs;
        xl[t]       = xg[t];
        xl[256 + t] = xg[256 + t];
    }
    // stage s[b]*x[b, band]: 8*32 = 256 entries, one per thread
    {
        const int bb = t >> 5, r = t & 31;
        sxs[bb][r] = s[b0 + bb] * x[(size_t)(b0 + bb) * DIM + i0 + r];
    }
    __syncthreads();

    float* outp = out + (size_t)b0 * DIM * DIM + (size_t)i0 * DIM;

    for (int b = 0; b < NB; ++b) {
        const f4 xj = ((const f4*)xs[b])[j4];
        f4* o4 = (f4*)(outp + (size_t)b * DIM * DIM);
        #pragma unroll
        for (int k = 0; k < 8; ++k) {
            const float sxv = sxs[b][irow * 8 + k];   // wave-uniform -> LDS broadcast
            f4 v = breg[k] + sxv * xj;
            o4[(irow * 8 + k) * 64 + j4] = v;
        }
    }
}

extern "C" void kernel_launch(void* const* d_in, const int* in_sizes, int n_in,
                              void* d_out, int out_size, void* d_ws, size_t ws_size,
                              hipStream_t stream) {
    const float* x  = (const float*)d_in[0];               // [2048, 256]
    const float* mf = (const float*)d_in[1];               // [4, 256, 256]
    const int* chart = (const int*)d_in[2];                // scalar
    float* out  = (float*)d_out;                           // [2048, 256, 256]
    float* base = (float*)d_ws;                            // 256*256 floats = 256 KiB
    float* s    = base + DIM * DIM;                        // 2048 floats

    prep_kernel<<<dim3(576), dim3(256), 0, stream>>>(mf, chart, x, base, s);
    main_kernel<<<dim3(BATCH / NB, DIM / RB), dim3(256), 0, stream>>>(x, s, base, out);
}